// Round 1
// baseline (332.707 us; speedup 1.0000x reference)
//
#include <hip/hip_runtime.h>
#include <cstdint>
#include <cstddef>

typedef __attribute__((ext_vector_type(8))) __bf16 bf16x8;
typedef __attribute__((ext_vector_type(4))) __bf16 bf16x4;
typedef __attribute__((ext_vector_type(4))) float  f32x4;

#define NPIX 4096
#define CHN  256

__device__ __forceinline__ void async_copy16(void* lds, const void* g) {
  __builtin_amdgcn_global_load_lds(
      (const __attribute__((address_space(1))) unsigned int*)g,
      (__attribute__((address_space(3))) unsigned int*)lds, 16, 0, 0);
}

// ---------- transpose + cast: x[B,C,N] f32 -> xT[B,N,C] bf16 ----------
__global__ __launch_bounds__(256) void k_transpose_cast(
    const float* __restrict__ X, __bf16* __restrict__ xT)
{
  __shared__ float tile[64][65];
  const int bid = blockIdx.x;
  const int b  = bid >> 8;         // 256 tiles per batch
  const int pt = (bid >> 2) & 63;  // pixel tile
  const int ct = bid & 3;          // channel tile
  const int tid = threadIdx.x;
  const int tc = tid & 63, tr = tid >> 6;
  const float* Xb = X + ((size_t)b*CHN + ct*64)*NPIX + pt*64;
#pragma unroll
  for (int i=0;i<16;++i) {
    int row = tr + i*4;
    tile[row][tc] = Xb[(size_t)row*NPIX + tc];
  }
  __syncthreads();
  __bf16* Tb = xT + ((size_t)b*NPIX + pt*64)*CHN + ct*64;
#pragma unroll
  for (int i=0;i<16;++i) {
    int prow = tr + i*4;
    Tb[(size_t)prow*CHN + tc] = (__bf16)tile[tc][prow];
  }
}

// ---------- weights: [O,I,3,3] f32 -> [tap][O][I] bf16, both convs ----------
__global__ __launch_bounds__(256) void k_wcast(
    const float* __restrict__ wv, const float* __restrict__ ww,
    __bf16* __restrict__ wvt, __bf16* __restrict__ wwt)
{
  int idx = blockIdx.x*256 + threadIdx.x;  // 589824 = 9*256*256 exactly
  int t = idx >> 16;
  int o = (idx >> 8) & 255;
  int i = idx & 255;
  size_t src = ((size_t)o*256 + i)*9 + t;
  wvt[idx] = (__bf16)wv[src];
  wwt[idx] = (__bf16)ww[src];
}

// ---------- conv3x3 as 9-tap GEMM: Y[b][o][p] = sum_t,i W9[t][o][i]*Bt[b][p+shift][i]
__global__ __launch_bounds__(256) void k_conv_tap(
    const __bf16* __restrict__ W9,   // [9][256][256]
    const __bf16* __restrict__ Bt,   // [B][4096][256] pixel-major
    const __bf16* __restrict__ zb,   // zero page (>=16B)
    float* __restrict__ Y)           // [B][256][4096]
{
  __shared__ __bf16 Alds[64*64];
  __shared__ __bf16 Blds[128*64];
  const int bid = blockIdx.x;
  const int b  = bid >> 7;          // 128 blocks per batch
  const int mt = (bid >> 5) & 3;    // 4 M-tiles of 64 out-channels
  const int nt = bid & 31;          // 32 N-tiles of 128 pixels
  const int m0 = mt << 6;
  const int p0 = nt << 7;
  const int tid = threadIdx.x;
  const int w = tid >> 6, l = tid & 63;
  const int l15 = l & 15, lhi = l >> 4;
  const int wr = (w >> 1) << 5;     // wave row offset: 0/32
  const int wc = (w & 1) << 6;      // wave col offset: 0/64

  const __bf16* Btb = Bt + ((size_t)b << 20);
  const f32x4 vzero = {0.f,0.f,0.f,0.f};
  f32x4 acc[2][4];
#pragma unroll
  for (int i=0;i<2;++i)
#pragma unroll
    for (int j=0;j<4;++j) acc[i][j] = vzero;

#pragma unroll 1
  for (int t=0; t<9; ++t) {
    const int dy = t/3 - 1, dx = t%3 - 1;
    const int dq = dy*64 + dx;
#pragma unroll 1
    for (int kc=0; kc<4; ++kc) {
      const int k0 = kc << 6;
      // A tile 64x64 (8 insts of 1KB, 2/wave)
#pragma unroll
      for (int i=0;i<2;++i) {
        int inst = w*2 + i;
        int s = inst*64 + l;
        int row = s >> 3, ch = s & 7;
        const __bf16* g = W9 + (size_t)t*65536 + (size_t)(m0+row)*256 + k0 + ch*8;
        async_copy16((char*)Alds + inst*1024, g);
      }
      // B tile 128x64 (16 insts, 4/wave), border-masked via zero page
#pragma unroll
      for (int i=0;i<4;++i) {
        int inst = w*4 + i;
        int s = inst*64 + l;
        int pp = s >> 3, ch = s & 7;
        int p = p0 + pp;
        int xx = (p & 63) + dx;
        int yy = (p >> 6) + dy;
        bool ok = ((unsigned)xx < 64u) & ((unsigned)yy < 64u);
        const __bf16* g = ok ? (Btb + (size_t)(p + dq)*256 + k0 + ch*8) : zb;
        async_copy16((char*)Blds + inst*1024, g);
      }
      asm volatile("s_waitcnt vmcnt(0)" ::: "memory");
      __syncthreads();
#pragma unroll
      for (int kk=0; kk<2; ++kk) {
        bf16x8 af[2], bfr[4];
#pragma unroll
        for (int i=0;i<2;++i)
          af[i] = *(const bf16x8*)(Alds + (wr + 16*i + l15)*64 + kk*32 + lhi*8);
#pragma unroll
        for (int j=0;j<4;++j)
          bfr[j] = *(const bf16x8*)(Blds + (wc + 16*j + l15)*64 + kk*32 + lhi*8);
#pragma unroll
        for (int i=0;i<2;++i)
#pragma unroll
          for (int j=0;j<4;++j)
            acc[i][j] = __builtin_amdgcn_mfma_f32_16x16x32_bf16(af[i], bfr[j], acc[i][j], 0,0,0);
      }
      __syncthreads();
    }
  }
  float* Yb = Y + ((size_t)b << 20);
#pragma unroll
  for (int i=0;i<2;++i)
#pragma unroll
    for (int j=0;j<4;++j)
#pragma unroll
      for (int r=0;r<4;++r) {
        int row = m0 + wr + 16*i + lhi*4 + r;
        int col = p0 + wc + 16*j + l15;
        Yb[(size_t)row*NPIX + col] = acc[i][j][r];
      }
}

// ---------- BN stats -> folded scale/shift (bias cancels, omitted) ----------
__global__ __launch_bounds__(256) void k_bn_stats(
    const float* __restrict__ Y, const float* __restrict__ gamma,
    const float* __restrict__ beta, float* __restrict__ scale,
    float* __restrict__ shift)
{
  const int c = blockIdx.x;
  const int tid = threadIdx.x;
  float s = 0.f, s2 = 0.f;
#pragma unroll 1
  for (int b=0;b<4;++b) {
    const float* p = Y + ((size_t)b*CHN + c)*NPIX;
    for (int i=tid; i<NPIX; i+=256) { float v = p[i]; s += v; s2 += v*v; }
  }
#pragma unroll
  for (int d=1; d<64; d<<=1) { s += __shfl_xor(s, d, 64); s2 += __shfl_xor(s2, d, 64); }
  __shared__ float rs[4], rs2[4];
  if ((tid & 63) == 0) { rs[tid>>6] = s; rs2[tid>>6] = s2; }
  __syncthreads();
  if (tid == 0) {
    float S  = rs[0]+rs[1]+rs[2]+rs[3];
    float S2 = rs2[0]+rs2[1]+rs2[2]+rs2[3];
    const float inv_n = 1.f/16384.f;
    float mean = S*inv_n;
    float var  = S2*inv_n - mean*mean;
    float rstd = rsqrtf(var + 1e-5f);
    float sc = gamma[c]*rstd;
    scale[c] = sc;
    shift[c] = beta[c] - mean*sc;
  }
}

// ---------- apply BN -> bf16 value [B][C][N] ----------
__global__ __launch_bounds__(256) void k_bn_apply_bf16(
    const float* __restrict__ Y, const float* __restrict__ scale,
    const float* __restrict__ shift, __bf16* __restrict__ V)
{
  size_t idx = ((size_t)blockIdx.x*256 + threadIdx.x)*4;
  int c = (int)((idx >> 12) & 255);
  float4 v = *(const float4*)(Y + idx);
  float sc = scale[c], sh = shift[c];
  bf16x4 r;
  r[0] = (__bf16)(v.x*sc + sh);
  r[1] = (__bf16)(v.y*sc + sh);
  r[2] = (__bf16)(v.z*sc + sh);
  r[3] = (__bf16)(v.w*sc + sh);
  *(bf16x4*)(V + idx) = r;
}

// ---------- apply BN + relu -> f32 output ----------
__global__ __launch_bounds__(256) void k_bn_relu(
    const float* __restrict__ Y, const float* __restrict__ scale,
    const float* __restrict__ shift, float* __restrict__ out)
{
  size_t idx = ((size_t)blockIdx.x*256 + threadIdx.x)*4;
  int c = (int)((idx >> 12) & 255);
  float4 v = *(const float4*)(Y + idx);
  float sc = scale[c], sh = shift[c];
  float4 r;
  r.x = fmaxf(v.x*sc + sh, 0.f);
  r.y = fmaxf(v.y*sc + sh, 0.f);
  r.z = fmaxf(v.z*sc + sh, 0.f);
  r.w = fmaxf(v.w*sc + sh, 0.f);
  *(float4*)(out + idx) = r;
}

// ---------- flash attention: O[b][n][c] = softmax(xT xT^T /16)[n,:] @ value[c,:]^T
__global__ __launch_bounds__(256) void k_attn(
    const __bf16* __restrict__ xT,   // [B][N][C]
    const __bf16* __restrict__ val,  // [B][C][N]
    __bf16* __restrict__ O)          // [B][N][C]
{
  __shared__ __bf16 Klds[64*256];    // K-tile [m-row][c], XOR-swizzled 16B chunks
  __shared__ __bf16 Vlds[256*64];    // V-tile [c][m], XOR-swizzled

  const int bid = blockIdx.x;
  const int b  = bid >> 6;
  const int q0 = (bid & 63) << 6;    // 64 q-rows per block
  const int tid = threadIdx.x;
  const int w = tid >> 6, l = tid & 63;
  const int l15 = l & 15, lhi = l >> 4;

  const __bf16* xTb = xT  + ((size_t)b << 20);
  const __bf16* vb  = val + ((size_t)b << 20);

  // Q fragments in registers, pre-scaled by C^-0.5 = 1/16 (exact in bf16)
  bf16x8 aq[8];
  {
    const __bf16* qp = xTb + (size_t)(q0 + w*16 + l15)*256 + lhi*8;
#pragma unroll
    for (int kc=0; kc<8; ++kc) {
      bf16x8 v = *(const bf16x8*)(qp + kc*32);
#pragma unroll
      for (int j=0;j<8;++j) v[j] = (__bf16)((float)v[j] * 0.0625f);
      aq[kc] = v;
    }
  }

  const f32x4 vzero = {0.f,0.f,0.f,0.f};
  float mrun[4], lrun[4];
  f32x4 o[16];
#pragma unroll
  for (int r=0;r<4;++r) { mrun[r] = -1e30f; lrun[r] = 0.f; }
#pragma unroll
  for (int cf=0; cf<16; ++cf) o[cf] = vzero;

#pragma unroll 1
  for (int mt=0; mt<64; ++mt) {
    const int m0 = mt << 6;
    // stage K: 64 rows x 256 c (32 insts, 8/wave), source pre-swizzled
#pragma unroll
    for (int i=0;i<8;++i) {
      int inst = w*8 + i;
      int s = inst*64 + l;
      int row = s >> 5, cs = s & 31;
      const __bf16* g = xTb + (size_t)(m0 + row)*256 + ((cs ^ (row & 7)) << 3);
      async_copy16((char*)Klds + inst*1024, g);
    }
    // stage V: 256 rows x 64 m (32 insts, 8/wave)
#pragma unroll
    for (int i=0;i<8;++i) {
      int inst = w*8 + i;
      int s = inst*64 + l;
      int row = s >> 3, cs = s & 7;
      const __bf16* g = vb + (size_t)row*NPIX + m0 + ((cs ^ (row & 7)) << 3);
      async_copy16((char*)Vlds + inst*1024, g);
    }
    asm volatile("s_waitcnt vmcnt(0)" ::: "memory");
    __syncthreads();

    // S = Q K^T  (rows n = lhi*4+r, cols m = l15+16*mf)
    f32x4 s4[4];
#pragma unroll
    for (int mf=0; mf<4; ++mf) {
      f32x4 acc = vzero;
      const int row = l15 + (mf<<4);
      const char* kbase = (const char*)Klds + row*512;
#pragma unroll
      for (int kc=0; kc<8; ++kc) {
        int csr = (kc<<2) + lhi;
        bf16x8 bk = *(const bf16x8*)(kbase + ((csr ^ (row & 7)) << 4));
        acc = __builtin_amdgcn_mfma_f32_16x16x32_bf16(aq[kc], bk, acc, 0,0,0);
      }
      s4[mf] = acc;
    }

    // online softmax
    float corr[4];
    __bf16 pb[4][4];
#pragma unroll
    for (int r=0;r<4;++r) {
      float mx = fmaxf(fmaxf(s4[0][r], s4[1][r]), fmaxf(s4[2][r], s4[3][r]));
#pragma unroll
      for (int d=1; d<16; d<<=1) mx = fmaxf(mx, __shfl_xor(mx, d, 64));
      float nm = fmaxf(mrun[r], mx);
      corr[r] = __expf(mrun[r] - nm);
      mrun[r] = nm;
      float ps = 0.f;
#pragma unroll
      for (int mf=0; mf<4; ++mf) {
        float p = __expf(s4[mf][r] - nm);
        __bf16 pbf = (__bf16)p;
        pb[mf][r] = pbf;
        ps += (float)pbf;
      }
#pragma unroll
      for (int d=1; d<16; d<<=1) ps += __shfl_xor(ps, d, 64);
      lrun[r] = lrun[r]*corr[r] + ps;
#pragma unroll
      for (int cf=0; cf<16; ++cf) o[cf][r] *= corr[r];
    }

    __syncthreads();   // all waves done reading K-tile; reuse it as P scratch

    // P: D-layout -> A-layout via per-wave LDS region (16 rows x 72 stride)
    __bf16* pl = Klds + w*1160;
#pragma unroll
    for (int mf=0; mf<4; ++mf)
#pragma unroll
      for (int r=0;r<4;++r)
        pl[(lhi*4+r)*72 + l15 + (mf<<4)] = pb[mf][r];

    bf16x8 pa[2];
#pragma unroll
    for (int kk=0;kk<2;++kk)
      pa[kk] = *(const bf16x8*)(pl + l15*72 + kk*32 + lhi*8);

    // O += P V^T  (cols c = l15+16*cf)
#pragma unroll
    for (int cf=0; cf<16; ++cf) {
      const int c = l15 + (cf<<4);
      const char* vbase = (const char*)Vlds + c*128;
#pragma unroll
      for (int kk=0; kk<2; ++kk) {
        int csr = (kk<<2) + lhi;
        bf16x8 bv = *(const bf16x8*)(vbase + ((csr ^ (c & 7)) << 4));
        o[cf] = __builtin_amdgcn_mfma_f32_16x16x32_bf16(pa[kk], bv, o[cf], 0,0,0);
      }
    }
    __syncthreads();
  }

  __bf16* Ob = O + ((size_t)b << 20);
  float inv[4];
#pragma unroll
  for (int r=0;r<4;++r) inv[r] = 1.f / lrun[r];
#pragma unroll
  for (int cf=0; cf<16; ++cf)
#pragma unroll
    for (int r=0;r<4;++r) {
      int row = q0 + w*16 + lhi*4 + r;
      Ob[(size_t)row*256 + l15 + (cf<<4)] = (__bf16)(o[cf][r] * inv[r]);
    }
}

extern "C" void kernel_launch(void* const* d_in, const int* in_sizes, int n_in,
                              void* d_out, int out_size, void* d_ws, size_t ws_size,
                              hipStream_t stream)
{
  const float* x     = (const float*)d_in[0];
  const float* wv    = (const float*)d_in[1];
  // d_in[2] = bv: bias shifts BN mean by the same amount -> cancels exactly
  const float* gv    = (const float*)d_in[3];
  const float* betav = (const float*)d_in[4];
  const float* ww    = (const float*)d_in[5];
  // d_in[6] = bw: cancels likewise
  const float* gw    = (const float*)d_in[7];
  const float* betaw = (const float*)d_in[8];
  float* out = (float*)d_out;

  char* ws = (char*)d_ws;
  __bf16* xT     = (__bf16*)(ws);                 // 8 MiB   [B][N][C]
  __bf16* val    = (__bf16*)(ws + 8388608);       // 8 MiB   [B][C][N]
  __bf16* Obuf   = (__bf16*)(ws + 16777216);      // 8 MiB   [B][N][C]
  __bf16* wvt    = (__bf16*)(ws + 25165824);      // 1.125 MiB [9][O][I]
  __bf16* wwt    = (__bf16*)(ws + 26345472);      // 1.125 MiB
  float* scale_v = (float*)(ws + 27525120);
  float* shift_v = (float*)(ws + 27526144);
  float* scale_w = (float*)(ws + 27527168);
  float* shift_w = (float*)(ws + 27528192);
  __bf16* zbuf   = (__bf16*)(ws + 27529216);      // 1 KiB zero page
  float* ybuf    = (float*)(ws + 27530240);       // 16 MiB  [B][C][N]
  if (ws_size < 44307456) return;

  hipMemsetAsync(zbuf, 0, 1024, stream);

  k_transpose_cast<<<1024, 256, 0, stream>>>(x, xT);
  k_wcast<<<2304, 256, 0, stream>>>(wv, ww, wvt, wwt);

  // value branch: conv1 + BN
  k_conv_tap<<<512, 256, 0, stream>>>(wvt, xT, zbuf, ybuf);
  k_bn_stats<<<256, 256, 0, stream>>>(ybuf, gv, betav, scale_v, shift_v);
  k_bn_apply_bf16<<<4096, 256, 0, stream>>>(ybuf, scale_v, shift_v, val);

  // attention
  k_attn<<<256, 256, 0, stream>>>(xT, val, Obuf);

  // output branch: conv2 + BN + relu
  k_conv_tap<<<512, 256, 0, stream>>>(wwt, Obuf, zbuf, ybuf);
  k_bn_stats<<<256, 256, 0, stream>>>(ybuf, gw, betaw, scale_w, shift_w);
  k_bn_relu<<<4096, 256, 0, stream>>>(ybuf, scale_w, shift_w, out);
}